// Round 1
// baseline (2215.713 us; speedup 1.0000x reference)
//
#include <hip/hip_runtime.h>

#define NN 65536
#define NE 524288
#define BG 512
#define DIN 128
#define HE 256
#define LATD 64
#define HD 512
#define NMX 128
#define NPAIR 8128
#define NST 7

// ---------------- CSR build ----------------
__global__ void vae_hist(const int* __restrict__ dst, int* __restrict__ cnt) {
    int e = blockIdx.x * 256 + threadIdx.x;
    if (e < NE) atomicAdd(&cnt[dst[e]], 1);
}

__global__ void vae_scan(const int* __restrict__ cnt, int* __restrict__ rs, int* __restrict__ cur) {
    __shared__ int sd[1024];
    __shared__ int carry_s;
    int tid = threadIdx.x;
    if (tid == 0) carry_s = 0;
    __syncthreads();
    for (int base = 0; base < NN; base += 1024) {
        int v = cnt[base + tid];
        sd[tid] = v;
        __syncthreads();
        int acc = v;
        for (int off = 1; off < 1024; off <<= 1) {
            int t = (tid >= off) ? sd[tid - off] : 0;
            __syncthreads();
            acc += t;
            sd[tid] = acc;
            __syncthreads();
        }
        int b0 = carry_s;
        rs[base + tid] = b0 + acc - v;
        cur[base + tid] = b0 + acc - v;
        __syncthreads();
        if (tid == 1023) carry_s = b0 + acc;
        __syncthreads();
    }
    if (tid == 0) rs[NN] = carry_s;
}

__global__ void vae_fill(const int* __restrict__ dst, int* __restrict__ cur, int* __restrict__ eid) {
    int e = blockIdx.x * 256 + threadIdx.x;
    if (e < NE) {
        int p = atomicAdd(&cur[dst[e]], 1);
        eid[p] = e;
    }
}

// canonicalize order (deterministic + matches reference edge order)
__global__ void vae_sort(const int* __restrict__ rs, int* __restrict__ eid,
                         const int* __restrict__ srcarr, int* __restrict__ csrc) {
    int n = blockIdx.x * 256 + threadIdx.x;
    if (n >= NN) return;
    int s = rs[n], e = rs[n + 1];
    for (int a = s + 1; a < e; ++a) {
        int key = eid[a];
        int b = a - 1;
        while (b >= s && eid[b] > key) { eid[b + 1] = eid[b]; --b; }
        eid[b + 1] = key;
    }
    for (int a = s; a < e; ++a) csrc[a] = srcarr[eid[a]];
}

__global__ void vae_pair(int* __restrict__ pi, int* __restrict__ pj) {
    int p = blockIdx.x * 256 + threadIdx.x;
    if (p >= NPAIR) return;
    int i = 0, off = 0;
    while (p >= off + (NMX - 1 - i)) { off += NMX - 1 - i; ++i; }
    pi[p] = i;
    pj[p] = i + 1 + (p - off);
}

// ---------------- aggregation: agg[n] = h[n] + sum_{e: dst=n} h[src[e]] ----------------
template <int D>
__global__ __launch_bounds__(256) void vae_agg(const float* __restrict__ H,
                                               const int* __restrict__ csrc,
                                               const int* __restrict__ rs,
                                               float* __restrict__ Agg) {
    const int gid = blockIdx.x * 256 + threadIdx.x;
    const int node = gid >> 6;
    const int lane = gid & 63;
    if (node >= NN) return;
    constexpr int V = D / 64;
    float acc[V];
    {
        const float* p = H + (size_t)node * D + lane * V;
        if constexpr (V == 4) {
            float4 v = *reinterpret_cast<const float4*>(p);
            acc[0] = v.x; acc[1] = v.y; acc[2] = v.z; acc[3] = v.w;
        } else {
            float2 v = *reinterpret_cast<const float2*>(p);
            acc[0] = v.x; acc[1] = v.y;
        }
    }
    const int s = rs[node], e = rs[node + 1];
    for (int a = s; a < e; ++a) {
        const float* p = H + (size_t)csrc[a] * D + lane * V;
        if constexpr (V == 4) {
            float4 v = *reinterpret_cast<const float4*>(p);
            acc[0] += v.x; acc[1] += v.y; acc[2] += v.z; acc[3] += v.w;
        } else {
            float2 v = *reinterpret_cast<const float2*>(p);
            acc[0] += v.x; acc[1] += v.y;
        }
    }
    float* o = Agg + (size_t)node * D + lane * V;
    if constexpr (V == 4) {
        float4 v; v.x = acc[0]; v.y = acc[1]; v.z = acc[2]; v.w = acc[3];
        *reinterpret_cast<float4*>(o) = v;
    } else {
        float2 v; v.x = acc[0]; v.y = acc[1];
        *reinterpret_cast<float2*>(o) = v;
    }
}

// ---------------- fused conv double-GEMM ----------------
// tile: 64 rows x 256 cols, 256 threads, thread tile 4x16
// t = bn(lrelu(A@W1+b1)); h = lrelu(t@W2+b2)
template <int K1>
__global__ __launch_bounds__(256) void vae_conv(const float* __restrict__ A,
                                                const float* __restrict__ W1, const float* __restrict__ B1,
                                                const float* __restrict__ G, const float* __restrict__ BE,
                                                const float* __restrict__ W2, const float* __restrict__ B2,
                                                float* __restrict__ Ho) {
    __shared__ float tls[64][260];
    const int tx = threadIdx.x & 15;
    const int ty = threadIdx.x >> 4;
    const int row0 = blockIdx.x * 64 + ty * 4;
    const int col0 = tx * 16;

    float acc[4][16];
#pragma unroll
    for (int r = 0; r < 4; r++)
#pragma unroll
        for (int c = 0; c < 16; c++) acc[r][c] = 0.f;

    for (int k = 0; k < K1; k += 4) {
        float a_[4][4];
#pragma unroll
        for (int r = 0; r < 4; r++) {
            float4 v = *reinterpret_cast<const float4*>(A + (size_t)(row0 + r) * K1 + k);
            a_[r][0] = v.x; a_[r][1] = v.y; a_[r][2] = v.z; a_[r][3] = v.w;
        }
#pragma unroll
        for (int kk = 0; kk < 4; kk++) {
            const float* wr = W1 + (size_t)(k + kk) * HE + col0;
            float bv[16];
            *reinterpret_cast<float4*>(&bv[0]) = *reinterpret_cast<const float4*>(wr);
            *reinterpret_cast<float4*>(&bv[4]) = *reinterpret_cast<const float4*>(wr + 4);
            *reinterpret_cast<float4*>(&bv[8]) = *reinterpret_cast<const float4*>(wr + 8);
            *reinterpret_cast<float4*>(&bv[12]) = *reinterpret_cast<const float4*>(wr + 12);
#pragma unroll
            for (int r = 0; r < 4; r++) {
                float a = a_[r][kk];
#pragma unroll
                for (int c = 0; c < 16; c++) acc[r][c] = fmaf(a, bv[c], acc[r][c]);
            }
        }
    }
    const float sq = sqrtf(1.0f + 1e-5f);
#pragma unroll
    for (int c = 0; c < 16; c++) {
        float b1 = B1[col0 + c];
        float sc = G[col0 + c] / sq;
        float be = BE[col0 + c];
#pragma unroll
        for (int r = 0; r < 4; r++) {
            float t = acc[r][c] + b1;
            t = t > 0.f ? t : 0.2f * t;
            t = t * sc + be;
            tls[ty * 4 + r][col0 + c] = t;
        }
    }
    __syncthreads();

#pragma unroll
    for (int r = 0; r < 4; r++)
#pragma unroll
        for (int c = 0; c < 16; c++) acc[r][c] = 0.f;

    for (int k = 0; k < HE; k += 4) {
        float a_[4][4];
#pragma unroll
        for (int r = 0; r < 4; r++) {
            float4 v = *reinterpret_cast<const float4*>(&tls[ty * 4 + r][k]);
            a_[r][0] = v.x; a_[r][1] = v.y; a_[r][2] = v.z; a_[r][3] = v.w;
        }
#pragma unroll
        for (int kk = 0; kk < 4; kk++) {
            const float* wr = W2 + (size_t)(k + kk) * HE + col0;
            float bv[16];
            *reinterpret_cast<float4*>(&bv[0]) = *reinterpret_cast<const float4*>(wr);
            *reinterpret_cast<float4*>(&bv[4]) = *reinterpret_cast<const float4*>(wr + 4);
            *reinterpret_cast<float4*>(&bv[8]) = *reinterpret_cast<const float4*>(wr + 8);
            *reinterpret_cast<float4*>(&bv[12]) = *reinterpret_cast<const float4*>(wr + 12);
#pragma unroll
            for (int r = 0; r < 4; r++) {
                float a = a_[r][kk];
#pragma unroll
                for (int c = 0; c < 16; c++) acc[r][c] = fmaf(a, bv[c], acc[r][c]);
            }
        }
    }
#pragma unroll
    for (int r = 0; r < 4; r++) {
        float hrow[16];
#pragma unroll
        for (int c = 0; c < 16; c++) {
            float h = acc[r][c] + B2[col0 + c];
            hrow[c] = h > 0.f ? h : 0.2f * h;
        }
#pragma unroll
        for (int cc = 0; cc < 4; cc++)
            *reinterpret_cast<float4*>(Ho + (size_t)(row0 + r) * HE + col0 + cc * 4) =
                *reinterpret_cast<float4*>(&hrow[cc * 4]);
    }
}

// ---------------- pooled -> bn -> fc -> mu -> d0 -> d1, one block per graph ----------------
__global__ __launch_bounds__(256) void vae_pooldec(const float* __restrict__ H, const float* __restrict__ stats,
                                                   const float* __restrict__ bng, const float* __restrict__ bnb,
                                                   const float* __restrict__ fcw, const float* __restrict__ fcb,
                                                   const float* __restrict__ muw, const float* __restrict__ mub,
                                                   const float* __restrict__ d0w, const float* __restrict__ d0b,
                                                   const float* __restrict__ d1w, const float* __restrict__ d1b,
                                                   float* __restrict__ Dm) {
    __shared__ float vin[264];
    __shared__ float fo[256];
    __shared__ float z[72];
    __shared__ float dd[512];
    const int b = blockIdx.x, t = threadIdx.x;

    float s = 0.f;
    const float* hp = H + (size_t)b * NMX * HE + t;
    for (int r = 0; r < NMX; r++) s += hp[(size_t)r * HE];
    vin[t] = s;
    if (t < NST) vin[HE + t] = stats[b * NST + t];
    __syncthreads();

    const float sq = sqrtf(1.0f + 1e-5f);
    float m0 = vin[t] * (bng[t] / sq) + bnb[t];
    float m1 = 0.f;
    if (t < NST) m1 = vin[HE + t] * (bng[HE + t] / sq) + bnb[HE + t];
    __syncthreads();
    vin[t] = m0;
    if (t < NST) vin[HE + t] = m1;
    __syncthreads();

    float a = fcb[t];
    for (int k = 0; k < HE + NST; k++) a = fmaf(vin[k], fcw[(size_t)k * HE + t], a);
    fo[t] = a;
    __syncthreads();

    if (t < LATD) {
        float m = mub[t];
        for (int k = 0; k < HE; k++) m = fmaf(fo[k], muw[(size_t)k * LATD + t], m);
        z[t] = m;
    }
    if (t >= LATD && t < LATD + NST) z[t] = stats[b * NST + (t - LATD)];
    __syncthreads();

    float a0 = d0b[t], a1 = d0b[t + 256];
    for (int k = 0; k < LATD + NST; k++) {
        float zk = z[k];
        a0 = fmaf(zk, d0w[(size_t)k * HD + t], a0);
        a1 = fmaf(zk, d0w[(size_t)k * HD + t + 256], a1);
    }
    dd[t] = a0 > 0.f ? a0 : 0.f;
    dd[t + 256] = a1 > 0.f ? a1 : 0.f;
    __syncthreads();

    float c0 = d1b[t], c1 = d1b[t + 256];
    for (int k = 0; k < HD; k++) {
        float dk = dd[k];
        c0 = fmaf(dk, d1w[(size_t)k * HD + t], c0);
        c1 = fmaf(dk, d1w[(size_t)k * HD + t + 256], c1);
    }
    Dm[(size_t)b * HD + t] = c0 > 0.f ? c0 : 0.f;
    Dm[(size_t)b * HD + t + 256] = c1 > 0.f ? c1 : 0.f;
}

__global__ void vae_diag(float* __restrict__ Out) {
    int t = blockIdx.x * 256 + threadIdx.x;  // 65536 = 512*128
    int b = t >> 7, i = t & 127;
    Out[(size_t)b * (NMX * NMX) + i * (NMX + 1)] = 0.f;
}

// ---------------- d2 GEMM fused with gumbel-argmax + adjacency scatter ----------------
// tile: 128 rows(graphs) x 128 cols, 256 threads, thread tile 8x8
__global__ __launch_bounds__(256) void vae_d2adj(const float* __restrict__ Dm, const float* __restrict__ W,
                                                 const float* __restrict__ Bb, const float* __restrict__ gum,
                                                 const int* __restrict__ PI, const int* __restrict__ PJ,
                                                 float* __restrict__ Out) {
    const int tx = threadIdx.x & 15, ty = threadIdx.x >> 4;
    const int col0 = blockIdx.x * 128 + tx * 8;
    const int row0 = blockIdx.y * 128 + ty * 8;
    float acc[8][8];
#pragma unroll
    for (int r = 0; r < 8; r++)
#pragma unroll
        for (int c = 0; c < 8; c++) acc[r][c] = 0.f;

    for (int k = 0; k < HD; k += 4) {
        float a_[8][4];
#pragma unroll
        for (int r = 0; r < 8; r++) {
            float4 v = *reinterpret_cast<const float4*>(Dm + (size_t)(row0 + r) * HD + k);
            a_[r][0] = v.x; a_[r][1] = v.y; a_[r][2] = v.z; a_[r][3] = v.w;
        }
#pragma unroll
        for (int kk = 0; kk < 4; kk++) {
            const float* wr = W + (size_t)(k + kk) * (2 * NPAIR) + col0;
            float bv[8];
            *reinterpret_cast<float4*>(&bv[0]) = *reinterpret_cast<const float4*>(wr);
            *reinterpret_cast<float4*>(&bv[4]) = *reinterpret_cast<const float4*>(wr + 4);
#pragma unroll
            for (int r = 0; r < 8; r++) {
                float a = a_[r][kk];
#pragma unroll
                for (int c = 0; c < 8; c++) acc[r][c] = fmaf(a, bv[c], acc[r][c]);
            }
        }
    }
    float bb[8];
#pragma unroll
    for (int c = 0; c < 8; c++) bb[c] = Bb[col0 + c];
#pragma unroll
    for (int r = 0; r < 8; r++) {
        int b_ = row0 + r;
#pragma unroll
        for (int q = 0; q < 4; q++) {
            int p = (col0 >> 1) + q;
            const float* gp = gum + ((size_t)b_ * NPAIR + p) * 2;
            float y0 = acc[r][2 * q] + bb[2 * q] + gp[0];
            float y1 = acc[r][2 * q + 1] + bb[2 * q + 1] + gp[1];
            float v = (y0 >= y1) ? 1.0f : 0.0f;
            int i = PI[p], j = PJ[p];
            Out[(size_t)b_ * (NMX * NMX) + i * NMX + j] = v;
            Out[(size_t)b_ * (NMX * NMX) + j * NMX + i] = v;
        }
    }
}

extern "C" void kernel_launch(void* const* d_in, const int* in_sizes, int n_in,
                              void* d_out, int out_size, void* d_ws, size_t ws_size,
                              hipStream_t stream) {
    const float* x = (const float*)d_in[0];
    const int* ei = (const int*)d_in[1];  // [0..NE) = src, [NE..2NE) = dst
    const float* stats = (const float*)d_in[3];
    const float* gum = (const float*)d_in[4];
    const float* cw1[3] = {(const float*)d_in[5], (const float*)d_in[11], (const float*)d_in[17]};
    const float* cb1[3] = {(const float*)d_in[6], (const float*)d_in[12], (const float*)d_in[18]};
    const float* cg[3] = {(const float*)d_in[7], (const float*)d_in[13], (const float*)d_in[19]};
    const float* cbe[3] = {(const float*)d_in[8], (const float*)d_in[14], (const float*)d_in[20]};
    const float* cw2[3] = {(const float*)d_in[9], (const float*)d_in[15], (const float*)d_in[21]};
    const float* cb2[3] = {(const float*)d_in[10], (const float*)d_in[16], (const float*)d_in[22]};
    const float* bng = (const float*)d_in[23];
    const float* bnb = (const float*)d_in[24];
    const float* fcw = (const float*)d_in[25];
    const float* fcb = (const float*)d_in[26];
    const float* muw = (const float*)d_in[27];
    const float* mub = (const float*)d_in[28];
    const float* d0w = (const float*)d_in[29];
    const float* d0b = (const float*)d_in[30];
    const float* d1w = (const float*)d_in[31];
    const float* d1b = (const float*)d_in[32];
    const float* d2w = (const float*)d_in[33];
    const float* d2b = (const float*)d_in[34];
    float* Out = (float*)d_out;

    char* wp = (char*)d_ws;
    auto alloc = [&](size_t bytes) -> void* {
        void* p = (void*)wp;
        wp += (bytes + 255) & ~(size_t)255;
        return p;
    };
    float* hA = (float*)alloc((size_t)NN * HE * 4);
    float* hB = (float*)alloc((size_t)NN * HE * 4);
    int* cnt = (int*)alloc((size_t)NN * 4);
    int* rs = (int*)alloc((size_t)(NN + 64) * 4);
    int* cur = (int*)alloc((size_t)NN * 4);
    int* eid = (int*)alloc((size_t)NE * 4);
    int* csrc = (int*)alloc((size_t)NE * 4);
    int* pi = (int*)alloc((size_t)NPAIR * 4);
    int* pj = (int*)alloc((size_t)NPAIR * 4);
    float* Dm = (float*)alloc((size_t)BG * HD * 4);

    const int* srcArr = ei;
    const int* dstArr = ei + NE;

    hipMemsetAsync(cnt, 0, (size_t)NN * 4, stream);
    vae_hist<<<NE / 256, 256, 0, stream>>>(dstArr, cnt);
    vae_scan<<<1, 1024, 0, stream>>>(cnt, rs, cur);
    vae_fill<<<NE / 256, 256, 0, stream>>>(dstArr, cur, eid);
    vae_sort<<<NN / 256, 256, 0, stream>>>(rs, eid, srcArr, csrc);
    vae_pair<<<(NPAIR + 255) / 256, 256, 0, stream>>>(pi, pj);

    // layer 0: x(N,128) -> hB(agg,128) -> hA(h,256)
    vae_agg<DIN><<<NN / 4, 256, 0, stream>>>(x, csrc, rs, hB);
    vae_conv<DIN><<<NN / 64, 256, 0, stream>>>(hB, cw1[0], cb1[0], cg[0], cbe[0], cw2[0], cb2[0], hA);
    // layer 1
    vae_agg<HE><<<NN / 4, 256, 0, stream>>>(hA, csrc, rs, hB);
    vae_conv<HE><<<NN / 64, 256, 0, stream>>>(hB, cw1[1], cb1[1], cg[1], cbe[1], cw2[1], cb2[1], hA);
    // layer 2
    vae_agg<HE><<<NN / 4, 256, 0, stream>>>(hA, csrc, rs, hB);
    vae_conv<HE><<<NN / 64, 256, 0, stream>>>(hB, cw1[2], cb1[2], cg[2], cbe[2], cw2[2], cb2[2], hA);

    vae_pooldec<<<BG, 256, 0, stream>>>(hA, stats, bng, bnb, fcw, fcb, muw, mub, d0w, d0b, d1w, d1b, Dm);

    vae_diag<<<(BG * NMX) / 256, 256, 0, stream>>>(Out);
    vae_d2adj<<<dim3((2 * NPAIR) / 128, BG / 128), 256, 0, stream>>>(Dm, d2w, d2b, gum, pi, pj, Out);
}